// Round 9
// baseline (208.463 us; speedup 1.0000x reference)
//
#include <hip/hip_runtime.h>

// ModularPathwayConv round 9:
//  R8 post-mortem: 4-deep gather chunking was NULL (45->47us) -> edge gather
//  latency was not the bound. Real bound: fused W2 epilogue = 256 ds_read_b128
//  per wave (~3072 LDS-port cyc x 24.4 waves/CU ~ 31us). Fix: un-fuse. 
//  node_accum stores H as bf16 (no LDS at all); new final_mfma does
//  out = H@W2 + deg*b2 on the matrix pipe (same scheme as precompute_mfma).

constexpr int TPB = 256;
constexpr int SCAN_B = 1024;

typedef __attribute__((ext_vector_type(8))) short short8;
typedef __attribute__((ext_vector_type(4))) float f32x4;

// fp32 -> bf16 round-to-nearest-even
__device__ inline unsigned short f2bf(float f) {
  unsigned u = __float_as_uint(f);
  unsigned r = u + 0x7fffu + ((u >> 16) & 1u);
  return (unsigned short)(r >> 16);
}

// ---------------- CSR build ----------------

__global__ void hist_rank(const int* __restrict__ ei, int* __restrict__ cnt,
                          int* __restrict__ rank, int E) {
  int e = blockIdx.x * blockDim.x + threadIdx.x;
  if (e < E) rank[e] = atomicAdd(&cnt[ei[E + e]], 1);
}

__global__ __launch_bounds__(SCAN_B) void scan_local(const int* __restrict__ cnt,
                                                     int* __restrict__ off,
                                                     int* __restrict__ bsum, int N) {
  __shared__ int s[SCAN_B];
  int i = blockIdx.x * SCAN_B + (int)threadIdx.x;
  int v = (i < N) ? cnt[i] : 0;
  s[threadIdx.x] = v;
  __syncthreads();
  for (int d = 1; d < SCAN_B; d <<= 1) {
    int t = (threadIdx.x >= d) ? s[threadIdx.x - d] : 0;
    __syncthreads();
    s[threadIdx.x] += t;
    __syncthreads();
  }
  if (i < N) off[i] = s[threadIdx.x] - v;
  if (threadIdx.x == SCAN_B - 1) bsum[blockIdx.x] = s[threadIdx.x];
}

__global__ __launch_bounds__(SCAN_B) void scan_bsum(int* __restrict__ bsum, int nb) {
  __shared__ int s[SCAN_B];
  int v = ((int)threadIdx.x < nb) ? bsum[threadIdx.x] : 0;
  s[threadIdx.x] = v;
  __syncthreads();
  for (int d = 1; d < SCAN_B; d <<= 1) {
    int t = (threadIdx.x >= d) ? s[threadIdx.x - d] : 0;
    __syncthreads();
    s[threadIdx.x] += t;
    __syncthreads();
  }
  if ((int)threadIdx.x < nb) bsum[threadIdx.x] = s[threadIdx.x] - v;
}

__global__ void scatter_edges(const int* __restrict__ ei, const float* __restrict__ ea,
                              const int* __restrict__ off, const int* __restrict__ bsum,
                              const int* __restrict__ rank, int2* __restrict__ sre, int E) {
  int e = blockIdx.x * blockDim.x + threadIdx.x;
  if (e >= E) return;
  int col = ei[E + e];
  int pos = off[col] + bsum[col >> 10] + rank[e];
  sre[pos] = make_int2(ei[e], __float_as_int(ea[e]));
}

// ---------------- precompute via MFMA: A = x@W1_top, Bp = x@W1_bot + b1 ----

__global__ __launch_bounds__(TPB) void precompute_mfma(
    const float* __restrict__ x, const float* __restrict__ W1,
    const float* __restrict__ b1,
    unsigned short* __restrict__ Abf, unsigned short* __restrict__ Bpbf, int N)
{
  __shared__ unsigned short sFrag[8 * 2 * 64 * 8];   // 16 KB

  for (int idx = threadIdx.x; idx < 8192; idx += TPB) {
    const int j  = idx & 7;
    const int l  = (idx >> 3) & 63;
    const int ks = (idx >> 9) & 1;
    const int ct = idx >> 10;
    const int k  = ks * 32 + ((l >> 4) << 3) + j;
    const int r  = k + 64 * (ct >> 2);
    const int c  = (ct & 3) * 16 + (l & 15);
    sFrag[idx] = f2bf(W1[r * 64 + c]);
  }
  __syncthreads();

  const int w = threadIdx.x >> 6;
  const int l = threadIdx.x & 63;
  const int q = l >> 4;
  const int m = l & 15;
  const int n0 = (blockIdx.x * 4 + w) * 16;
  if (n0 >= N) return;

  short8 bfrag[8][2];
#pragma unroll
  for (int ct = 0; ct < 8; ++ct)
#pragma unroll
    for (int ks = 0; ks < 2; ++ks)
      bfrag[ct][ks] =
          *reinterpret_cast<const short8*>(&sFrag[(ct * 2 + ks) * 512 + l * 8]);

  const int nA = (n0 + m < N) ? (n0 + m) : (N - 1);
  const float* xr = x + (size_t)nA * 64 + q * 8;
  short8 afrag[2];
#pragma unroll
  for (int ks = 0; ks < 2; ++ks) {
    float4 v0 = *reinterpret_cast<const float4*>(xr + ks * 32);
    float4 v1 = *reinterpret_cast<const float4*>(xr + ks * 32 + 4);
    short8 a;
    a[0] = (short)f2bf(v0.x); a[1] = (short)f2bf(v0.y);
    a[2] = (short)f2bf(v0.z); a[3] = (short)f2bf(v0.w);
    a[4] = (short)f2bf(v1.x); a[5] = (short)f2bf(v1.y);
    a[6] = (short)f2bf(v1.z); a[7] = (short)f2bf(v1.w);
    afrag[ks] = a;
  }

  f32x4 acc[8];
#pragma unroll
  for (int ct = 0; ct < 8; ++ct) {
    const float bv = (ct >= 4) ? b1[(ct - 4) * 16 + m] : 0.0f;
    acc[ct] = (f32x4){bv, bv, bv, bv};
  }

#pragma unroll
  for (int ct = 0; ct < 8; ++ct)
#pragma unroll
    for (int ks = 0; ks < 2; ++ks)
      acc[ct] = __builtin_amdgcn_mfma_f32_16x16x32_bf16(
          afrag[ks], bfrag[ct][ks], acc[ct], 0, 0, 0);

#pragma unroll
  for (int ct = 0; ct < 8; ++ct) {
    unsigned short* dst = (ct < 4) ? Abf : Bpbf;
    const int ch = (ct & 3) * 16 + m;
#pragma unroll
    for (int r = 0; r < 4; ++r) {
      const int node = n0 + q * 4 + r;
      if (node < N) dst[(size_t)node * 64 + ch] = f2bf(acc[ct][r]);
    }
  }
}

// ---------------- node accumulate ONLY: H[n] = sum relu(ea*A[row]+Bp[n]) ----
// 4 lanes/node, no LDS, no syncthreads; H stored bf16. Zero atomics.

__global__ __launch_bounds__(TPB) void node_accum(
    const unsigned int* __restrict__ Abf, const unsigned int* __restrict__ Bpbf,
    const int2* __restrict__ sre, const int* __restrict__ off,
    const int* __restrict__ bsum, const int* __restrict__ cnt,
    unsigned short* __restrict__ Hbf, int N)
{
  const int g = blockIdx.x * TPB + (int)threadIdx.x;
  const int n = g >> 2;
  const int q = g & 3;
  if (n >= N) return;

  const int start = off[n] + bsum[n >> 10];
  const int deg = cnt[n];

  float bpf[16];
  {
    const uint4* brow = reinterpret_cast<const uint4*>(Bpbf) + (size_t)n * 8 + q * 2;
    uint4 b0 = brow[0], b1v = brow[1];
    const unsigned int bu[8] = {b0.x, b0.y, b0.z, b0.w, b1v.x, b1v.y, b1v.z, b1v.w};
#pragma unroll
    for (int j = 0; j < 8; ++j) {
      bpf[2 * j]     = __uint_as_float(bu[j] << 16);
      bpf[2 * j + 1] = __uint_as_float(bu[j] & 0xffff0000u);
    }
  }

  float acc[16];
#pragma unroll
  for (int j = 0; j < 16; ++j) acc[j] = 0.f;

  // 4-deep chunked edge loop (8 independent dwordx4 loads in flight)
  for (int t0 = 0; t0 < deg; t0 += 4) {
    const int rem = deg - t0;
    int2 er[4];
#pragma unroll
    for (int i = 0; i < 4; ++i)
      er[i] = (i < rem) ? sre[start + t0 + i] : make_int2(0, 0);

    uint4 A0[4], A1[4];
#pragma unroll
    for (int i = 0; i < 4; ++i) {
      const uint4* ar =
          reinterpret_cast<const uint4*>(Abf) + (size_t)er[i].x * 8 + q * 2;
      A0[i] = ar[0];
      A1[i] = ar[1];
    }

#pragma unroll
    for (int i = 0; i < 4; ++i) {
      if (i >= rem) break;
      const float eav = __int_as_float(er[i].y);
      const unsigned int au[8] = {A0[i].x, A0[i].y, A0[i].z, A0[i].w,
                                  A1[i].x, A1[i].y, A1[i].z, A1[i].w};
#pragma unroll
      for (int j = 0; j < 8; ++j) {
        float lo = __uint_as_float(au[j] << 16);
        float hi = __uint_as_float(au[j] & 0xffff0000u);
        acc[2 * j]     += fmaxf(fmaf(eav, lo, bpf[2 * j]), 0.f);
        acc[2 * j + 1] += fmaxf(fmaf(eav, hi, bpf[2 * j + 1]), 0.f);
      }
    }
  }

  // pack 16 fp32 -> bf16, store 32B (2x uint4)
  uint4 h0, h1;
  unsigned int* h0w = &h0.x;
  unsigned int* h1w = &h1.x;
#pragma unroll
  for (int j = 0; j < 4; ++j) {
    h0w[j] = (unsigned int)f2bf(acc[2 * j]) |
             ((unsigned int)f2bf(acc[2 * j + 1]) << 16);
    h1w[j] = (unsigned int)f2bf(acc[8 + 2 * j]) |
             ((unsigned int)f2bf(acc[8 + 2 * j + 1]) << 16);
  }
  uint4* hrow = reinterpret_cast<uint4*>(Hbf + (size_t)n * 64) + q * 2;
  hrow[0] = h0;
  hrow[1] = h1;
}

// ---------------- final GEMM via MFMA: out = H@W2 + deg*b2 ----------------

__global__ __launch_bounds__(TPB) void final_mfma(
    const unsigned short* __restrict__ Hbf, const float* __restrict__ W2,
    const float* __restrict__ b2, const int* __restrict__ cnt,
    float* __restrict__ out, int N)
{
  __shared__ unsigned short sFrag[4 * 2 * 64 * 8];   // 8 KB

  for (int idx = threadIdx.x; idx < 4096; idx += TPB) {
    const int j  = idx & 7;
    const int l  = (idx >> 3) & 63;
    const int ks = (idx >> 9) & 1;
    const int ct = idx >> 10;
    const int k  = ks * 32 + ((l >> 4) << 3) + j;
    const int c  = ct * 16 + (l & 15);
    sFrag[idx] = f2bf(W2[k * 64 + c]);
  }
  __syncthreads();

  const int w = threadIdx.x >> 6;
  const int l = threadIdx.x & 63;
  const int q = l >> 4;
  const int m = l & 15;
  const int n0 = (blockIdx.x * 4 + w) * 16;
  if (n0 >= N) return;

  short8 bfrag[4][2];
#pragma unroll
  for (int ct = 0; ct < 4; ++ct)
#pragma unroll
    for (int ks = 0; ks < 2; ++ks)
      bfrag[ct][ks] =
          *reinterpret_cast<const short8*>(&sFrag[(ct * 2 + ks) * 512 + l * 8]);

  const int nA = (n0 + m < N) ? (n0 + m) : (N - 1);
  short8 afrag[2];
  afrag[0] = *reinterpret_cast<const short8*>(Hbf + (size_t)nA * 64 + q * 8);
  afrag[1] = *reinterpret_cast<const short8*>(Hbf + (size_t)nA * 64 + 32 + q * 8);

  // deg for the bias rows this lane owns (D rows = n0 + q*4 + r)
  float dg[4];
#pragma unroll
  for (int r = 0; r < 4; ++r) {
    const int node = n0 + q * 4 + r;
    dg[r] = (node < N) ? (float)cnt[node] : 0.0f;
  }

  f32x4 acc[4];
#pragma unroll
  for (int ct = 0; ct < 4; ++ct) {
    const float bv = b2[ct * 16 + m];
    acc[ct] = (f32x4){dg[0] * bv, dg[1] * bv, dg[2] * bv, dg[3] * bv};
  }

#pragma unroll
  for (int ct = 0; ct < 4; ++ct)
#pragma unroll
    for (int ks = 0; ks < 2; ++ks)
      acc[ct] = __builtin_amdgcn_mfma_f32_16x16x32_bf16(
          afrag[ks], bfrag[ct][ks], acc[ct], 0, 0, 0);

#pragma unroll
  for (int ct = 0; ct < 4; ++ct) {
    const int ch = ct * 16 + m;
#pragma unroll
    for (int r = 0; r < 4; ++r) {
      const int node = n0 + q * 4 + r;
      if (node < N) out[(size_t)node * 64 + ch] = acc[ct][r];
    }
  }
}

// ---------------- fallback (round-1 path, if ws too small) ----------------

__global__ __launch_bounds__(TPB) void edge_mlp_atomic(
    const float* __restrict__ x, const int* __restrict__ ei,
    const float* __restrict__ eattr, const float* __restrict__ W1,
    const float* __restrict__ b1, const float* __restrict__ W2,
    const float* __restrict__ b2, float* __restrict__ out, int E)
{
  __shared__ float sW1[128 * 64];
  __shared__ float sW2[64 * 64];
  __shared__ float sB1[64];
  __shared__ float sB2[64];
  for (int i = threadIdx.x; i < 128 * 64 / 4; i += TPB)
    reinterpret_cast<float4*>(sW1)[i] = reinterpret_cast<const float4*>(W1)[i];
  for (int i = threadIdx.x; i < 64 * 64 / 4; i += TPB)
    reinterpret_cast<float4*>(sW2)[i] = reinterpret_cast<const float4*>(W2)[i];
  if (threadIdx.x < 64) { sB1[threadIdx.x] = b1[threadIdx.x]; sB2[threadIdx.x] = b2[threadIdx.x]; }
  __syncthreads();
  const int e = blockIdx.x * TPB + (int)threadIdx.x;
  if (e >= E) return;
  const int row = ei[e];
  const int col = ei[E + e];
  const float scale = eattr[e];
  float h[64];
#pragma unroll
  for (int o = 0; o < 64; ++o) h[o] = sB1[o];
#pragma unroll
  for (int half = 0; half < 2; ++half) {
    const float4* src = reinterpret_cast<const float4*>(x + (size_t)(half ? col : row) * 64);
    const float sc = half ? 1.0f : scale;
    const float* wb = sW1 + half * 64 * 64;
    for (int kc = 0; kc < 16; ++kc) {
      float4 cv = src[kc];
      cv.x *= sc; cv.y *= sc; cv.z *= sc; cv.w *= sc;
      const float* wr = wb + kc * 4 * 64;
#pragma unroll
      for (int kk = 0; kk < 4; ++kk) {
        const float c = (&cv.x)[kk];
#pragma unroll
        for (int o = 0; o < 64; ++o) h[o] = fmaf(c, wr[kk * 64 + o], h[o]);
      }
    }
  }
#pragma unroll
  for (int o = 0; o < 64; ++o) h[o] = fmaxf(h[o], 0.0f);
  float* outrow = out + (size_t)col * 64;
#pragma unroll
  for (int oc = 0; oc < 4; ++oc) {
    float m[16];
#pragma unroll
    for (int j = 0; j < 16; ++j) m[j] = sB2[oc * 16 + j];
#pragma unroll
    for (int k = 0; k < 64; ++k) {
      const float hk = h[k];
      const float* wr = sW2 + k * 64 + oc * 16;
#pragma unroll
      for (int j = 0; j < 16; ++j) m[j] = fmaf(hk, wr[j], m[j]);
    }
#pragma unroll
    for (int j = 0; j < 16; ++j) atomicAdd(outrow + oc * 16 + j, m[j]);
  }
}

// ---------------- launch ----------------

extern "C" void kernel_launch(void* const* d_in, const int* in_sizes, int n_in,
                              void* d_out, int out_size, void* d_ws, size_t ws_size,
                              hipStream_t stream) {
  const float* x  = (const float*)d_in[0];
  const int*   ei = (const int*)d_in[1];   // [2,E] int32
  const float* ea = (const float*)d_in[2];
  const float* b1 = (const float*)d_in[4];
  const float* W1 = (const float*)d_in[3];
  const float* W2 = (const float*)d_in[5];
  const float* b2 = (const float*)d_in[6];
  float* out = (float*)d_out;
  const int E = in_sizes[2];
  const int N = in_sizes[0] / 64;
  const int nb = (N + SCAN_B - 1) / SCAN_B;

  // ws layout: sre[E] int2 | rank[E] | cnt[N] | off[N] | bsum[SCAN_B]
  //            | Abf[N*64 u16] | Bpbf[N*64 u16] | Hbf[N*64 u16]
  auto align16 = [](size_t v) { return (v + 15) & ~(size_t)15; };
  size_t o_sre  = 0;
  size_t o_rank = align16(o_sre + (size_t)E * 8);
  size_t o_cnt  = align16(o_rank + (size_t)E * 4);
  size_t o_off  = align16(o_cnt + (size_t)N * 4);
  size_t o_bsum = align16(o_off + (size_t)N * 4);
  size_t o_A    = align16(o_bsum + (size_t)SCAN_B * 4);
  size_t o_Bp   = align16(o_A + (size_t)N * 128);
  size_t o_H    = align16(o_Bp + (size_t)N * 128);
  size_t need   = o_H + (size_t)N * 128;

  if (ws_size < need || nb > SCAN_B) {
    hipMemsetAsync(d_out, 0, (size_t)out_size * sizeof(float), stream);
    const int blocks = (E + TPB - 1) / TPB;
    edge_mlp_atomic<<<blocks, TPB, 0, stream>>>(x, ei, ea, W1, b1, W2, b2, out, E);
    return;
  }

  char* ws = (char*)d_ws;
  int2* sre  = (int2*)(ws + o_sre);
  int*  rank = (int*)(ws + o_rank);
  int*  cnt  = (int*)(ws + o_cnt);
  int*  off  = (int*)(ws + o_off);
  int*  bsum = (int*)(ws + o_bsum);
  unsigned short* Abf  = (unsigned short*)(ws + o_A);
  unsigned short* Bpbf = (unsigned short*)(ws + o_Bp);
  unsigned short* Hbf  = (unsigned short*)(ws + o_H);

  hipMemsetAsync(cnt, 0, (size_t)N * sizeof(int), stream);

  const int eblocks = (E + TPB - 1) / TPB;
  const int nblocks4 = (4 * N + TPB - 1) / TPB;
  const int tblocks = ((N + 15) / 16 + 3) / 4;

  hist_rank<<<eblocks, TPB, 0, stream>>>(ei, cnt, rank, E);
  scan_local<<<nb, SCAN_B, 0, stream>>>(cnt, off, bsum, N);
  scan_bsum<<<1, SCAN_B, 0, stream>>>(bsum, nb);
  scatter_edges<<<eblocks, TPB, 0, stream>>>(ei, ea, off, bsum, rank, sre, E);
  precompute_mfma<<<tblocks, TPB, 0, stream>>>(x, W1, b1, Abf, Bpbf, N);
  node_accum<<<nblocks4, TPB, 0, stream>>>((const unsigned int*)Abf,
                                           (const unsigned int*)Bpbf,
                                           sre, off, bsum, cnt, Hbf, N);
  final_mfma<<<tblocks, TPB, 0, stream>>>(Hbf, W2, b2, cnt, out, N);
}

// Round 10
// 196.350 us; speedup vs baseline: 1.0617x; 1.0617x over previous
//
#include <hip/hip_runtime.h>

// ModularPathwayConv round 10:
//  R9 post-mortem: un-fuse was net-neutral; every kernel now < 42us and
//  transaction-bound. Three floors attacked:
//  1. A stored fp8-e4m3 (HW cvt_pk builtins) -> gather FETCH halves again.
//  2. sre packed to 4B (row<<15 | q15(ea)) -> scatter write amplification halves.
//  3. Scan kernels deleted: CSR bases via block-scan + atomic ticket (order
//     irrelevant for correctness), fused into the precompute dispatch. 6 launches.

constexpr int TPB = 256;

typedef __attribute__((ext_vector_type(8))) short short8;
typedef __attribute__((ext_vector_type(4))) float f32x4;
typedef __attribute__((ext_vector_type(2))) float f32x2;

// fp32 -> bf16 round-to-nearest-even
__device__ inline unsigned short f2bf(float f) {
  unsigned u = __float_as_uint(f);
  unsigned r = u + 0x7fffu + ((u >> 16) & 1u);
  return (unsigned short)(r >> 16);
}

// ---- fp8 e4m3 encode/decode (HW builtins when available) ----
#if __has_builtin(__builtin_amdgcn_cvt_pk_fp8_f32) && __has_builtin(__builtin_amdgcn_cvt_pk_f32_fp8)
#define FP8_HW 1
#else
#define FP8_HW 0
#endif

__device__ inline unsigned f32_to_fp8(float f) {
#if FP8_HW
  return (unsigned)__builtin_amdgcn_cvt_pk_fp8_f32(f, f, 0, false) & 0xFFu;
#else
  unsigned u = __float_as_uint(f);
  unsigned s = u >> 31;
  float af = fabsf(f);
  if (af >= 448.f) return (s << 7) | 0x7E;
  if (af < 0.015625f) {
    int m = (int)(af * 512.0f + 0.5f);
    if (m > 7) m = 7;
    return (s << 7) | m;
  }
  unsigned r = (u & 0x7FFFFFFFu) + 0x7FFFFu + ((u >> 20) & 1u);
  int e = (int)((r >> 23) & 0xFF) - 127 + 7;
  if (e >= 16) return (s << 7) | 0x7E;
  return (s << 7) | ((unsigned)e << 3) | ((r >> 20) & 7);
#endif
}

// decode 4 fp8 packed in a u32 -> 4 floats
__device__ inline void fp8x4_to_f32(unsigned w, float* o) {
#if FP8_HW
  f32x2 lo = __builtin_amdgcn_cvt_pk_f32_fp8((int)w, false);
  f32x2 hi = __builtin_amdgcn_cvt_pk_f32_fp8((int)w, true);
  o[0] = lo[0]; o[1] = lo[1]; o[2] = hi[0]; o[3] = hi[1];
#else
#pragma unroll
  for (int i = 0; i < 4; ++i) {
    unsigned b = (w >> (8 * i)) & 0xFF;
    unsigned s = (b >> 7) & 1, e = (b >> 3) & 0xF, m = b & 7;
    float v;
    if (e == 0) { v = (float)m * 0.001953125f; v = s ? -v : v; }
    else v = __uint_as_float((s << 31) | ((e - 7 + 127) << 23) | (m << 20));
    o[i] = v;
  }
#endif
}

// ---------------- CSR build ----------------

__global__ void hist_rank(const int* __restrict__ ei, int* __restrict__ cnt,
                          int* __restrict__ rank, int E) {
  int e = blockIdx.x * blockDim.x + threadIdx.x;
  if (e < E) rank[e] = atomicAdd(&cnt[ei[E + e]], 1);
}

// atomic-free scatter with 4B packed record: (row << 15) | q15(ea)
__global__ void scatter_edges(const int* __restrict__ ei, const float* __restrict__ ea,
                              const int* __restrict__ off, const int* __restrict__ rank,
                              unsigned int* __restrict__ srp, int E) {
  int e = blockIdx.x * blockDim.x + threadIdx.x;
  if (e >= E) return;
  int col = ei[E + e];
  int pos = off[col] + rank[e];
  unsigned q = (unsigned)(ea[e] * 32767.0f + 0.5f);
  if (q > 32767u) q = 32767u;
  srp[pos] = ((unsigned)ei[e] << 15) | q;
}

// ---------------- fused: CSR base assignment | precompute MFMA ----------------
// Blocks [0, bb): off[n] = ticket-scan of cnt (segment ORDER is irrelevant,
// only disjointness matters). Blocks [bb, ...): A = x@W1_top (fp8 out),
// Bp = x@W1_bot + b1 (bf16 out) via mfma_f32_16x16x32_bf16.

__global__ __launch_bounds__(TPB) void base_and_precompute(
    const float* __restrict__ x, const float* __restrict__ W1,
    const float* __restrict__ b1, const int* __restrict__ cnt,
    int* __restrict__ off, int* __restrict__ total,
    unsigned char* __restrict__ Af8, unsigned short* __restrict__ Bpbf,
    int N, int bb)
{
  if ((int)blockIdx.x < bb) {
    // ---- CSR base assignment: block-local scan + one global atomic ----
    __shared__ int sScan[TPB];
    __shared__ int sBase;
    const int i = blockIdx.x * TPB + (int)threadIdx.x;
    const int v = (i < N) ? cnt[i] : 0;
    sScan[threadIdx.x] = v;
    __syncthreads();
    for (int d = 1; d < TPB; d <<= 1) {
      int t = ((int)threadIdx.x >= d) ? sScan[threadIdx.x - d] : 0;
      __syncthreads();
      sScan[threadIdx.x] += t;
      __syncthreads();
    }
    if (threadIdx.x == TPB - 1) sBase = atomicAdd(total, sScan[TPB - 1]);
    __syncthreads();
    if (i < N) off[i] = sBase + sScan[threadIdx.x] - v;
    return;
  }

  // ---- precompute tiles ----
  __shared__ unsigned short sFrag[8 * 2 * 64 * 8];   // 16 KB

  for (int idx = threadIdx.x; idx < 8192; idx += TPB) {
    const int j  = idx & 7;
    const int l  = (idx >> 3) & 63;
    const int ks = (idx >> 9) & 1;
    const int ct = idx >> 10;
    const int k  = ks * 32 + ((l >> 4) << 3) + j;
    const int r  = k + 64 * (ct >> 2);
    const int c  = (ct & 3) * 16 + (l & 15);
    sFrag[idx] = f2bf(W1[r * 64 + c]);
  }
  __syncthreads();

  const int w = threadIdx.x >> 6;
  const int l = threadIdx.x & 63;
  const int q = l >> 4;
  const int m = l & 15;
  const int n0 = (((int)blockIdx.x - bb) * 4 + w) * 16;
  if (n0 >= N) return;

  short8 bfrag[8][2];
#pragma unroll
  for (int ct = 0; ct < 8; ++ct)
#pragma unroll
    for (int ks = 0; ks < 2; ++ks)
      bfrag[ct][ks] =
          *reinterpret_cast<const short8*>(&sFrag[(ct * 2 + ks) * 512 + l * 8]);

  const int nA = (n0 + m < N) ? (n0 + m) : (N - 1);
  const float* xr = x + (size_t)nA * 64 + q * 8;
  short8 afrag[2];
#pragma unroll
  for (int ks = 0; ks < 2; ++ks) {
    float4 v0 = *reinterpret_cast<const float4*>(xr + ks * 32);
    float4 v1 = *reinterpret_cast<const float4*>(xr + ks * 32 + 4);
    short8 a;
    a[0] = (short)f2bf(v0.x); a[1] = (short)f2bf(v0.y);
    a[2] = (short)f2bf(v0.z); a[3] = (short)f2bf(v0.w);
    a[4] = (short)f2bf(v1.x); a[5] = (short)f2bf(v1.y);
    a[6] = (short)f2bf(v1.z); a[7] = (short)f2bf(v1.w);
    afrag[ks] = a;
  }

  f32x4 acc[8];
#pragma unroll
  for (int ct = 0; ct < 8; ++ct) {
    const float bv = (ct >= 4) ? b1[(ct - 4) * 16 + m] : 0.0f;
    acc[ct] = (f32x4){bv, bv, bv, bv};
  }

#pragma unroll
  for (int ct = 0; ct < 8; ++ct)
#pragma unroll
    for (int ks = 0; ks < 2; ++ks)
      acc[ct] = __builtin_amdgcn_mfma_f32_16x16x32_bf16(
          afrag[ks], bfrag[ct][ks], acc[ct], 0, 0, 0);

#pragma unroll
  for (int ct = 0; ct < 8; ++ct) {
    const int ch = (ct & 3) * 16 + m;
#pragma unroll
    for (int r = 0; r < 4; ++r) {
      const int node = n0 + q * 4 + r;
      if (node >= N) continue;
      if (ct < 4)
        Af8[(size_t)node * 64 + ch] = (unsigned char)f32_to_fp8(acc[ct][r]);
      else
        Bpbf[(size_t)node * 64 + ch] = f2bf(acc[ct][r]);
    }
  }
}

// ---------------- node accumulate: H[n] = sum relu(ea*A[row]+Bp[n]) ----
// 4 lanes/node; A fp8 gather (16B = lane's 16 channels); no LDS; zero atomics.

__global__ __launch_bounds__(TPB) void node_accum(
    const unsigned char* __restrict__ Af8, const unsigned int* __restrict__ Bpbf,
    const unsigned int* __restrict__ srp, const int* __restrict__ off,
    const int* __restrict__ cnt, unsigned short* __restrict__ Hbf, int N)
{
  const int g = blockIdx.x * TPB + (int)threadIdx.x;
  const int n = g >> 2;
  const int q = g & 3;
  if (n >= N) return;

  const int start = off[n];
  const int deg = cnt[n];

  float bpf[16];
  {
    const uint4* brow = reinterpret_cast<const uint4*>(Bpbf) + (size_t)n * 8 + q * 2;
    uint4 b0 = brow[0], b1v = brow[1];
    const unsigned int bu[8] = {b0.x, b0.y, b0.z, b0.w, b1v.x, b1v.y, b1v.z, b1v.w};
#pragma unroll
    for (int j = 0; j < 8; ++j) {
      bpf[2 * j]     = __uint_as_float(bu[j] << 16);
      bpf[2 * j + 1] = __uint_as_float(bu[j] & 0xffff0000u);
    }
  }

  float acc[16];
#pragma unroll
  for (int j = 0; j < 16; ++j) acc[j] = 0.f;

  // 4-deep chunks: 4 packed records + 4 independent 16B A-loads in flight
  for (int t0 = 0; t0 < deg; t0 += 4) {
    const int rem = deg - t0;
    unsigned er[4];
#pragma unroll
    for (int i = 0; i < 4; ++i)
      er[i] = (i < rem) ? srp[start + t0 + i] : 0u;

    uint4 Av[4];
#pragma unroll
    for (int i = 0; i < 4; ++i) {
      const size_t row = (size_t)(er[i] >> 15);
      Av[i] = *reinterpret_cast<const uint4*>(Af8 + row * 64 + q * 16);
    }

#pragma unroll
    for (int i = 0; i < 4; ++i) {
      if (i >= rem) break;
      const float eav = (float)(er[i] & 0x7FFFu) * (1.0f / 32767.0f);
      float a[16];
      fp8x4_to_f32(Av[i].x, a);
      fp8x4_to_f32(Av[i].y, a + 4);
      fp8x4_to_f32(Av[i].z, a + 8);
      fp8x4_to_f32(Av[i].w, a + 12);
#pragma unroll
      for (int j = 0; j < 16; ++j)
        acc[j] += fmaxf(fmaf(eav, a[j], bpf[j]), 0.f);
    }
  }

  // pack 16 fp32 -> bf16, store 32B
  uint4 h0, h1;
  unsigned int* h0w = &h0.x;
  unsigned int* h1w = &h1.x;
#pragma unroll
  for (int j = 0; j < 4; ++j) {
    h0w[j] = (unsigned int)f2bf(acc[2 * j]) |
             ((unsigned int)f2bf(acc[2 * j + 1]) << 16);
    h1w[j] = (unsigned int)f2bf(acc[8 + 2 * j]) |
             ((unsigned int)f2bf(acc[8 + 2 * j + 1]) << 16);
  }
  uint4* hrow = reinterpret_cast<uint4*>(Hbf + (size_t)n * 64) + q * 2;
  hrow[0] = h0;
  hrow[1] = h1;
}

// ---------------- final GEMM via MFMA: out = H@W2 + deg*b2 ----------------

__global__ __launch_bounds__(TPB) void final_mfma(
    const unsigned short* __restrict__ Hbf, const float* __restrict__ W2,
    const float* __restrict__ b2, const int* __restrict__ cnt,
    float* __restrict__ out, int N)
{
  __shared__ unsigned short sFrag[4 * 2 * 64 * 8];   // 8 KB

  for (int idx = threadIdx.x; idx < 4096; idx += TPB) {
    const int j  = idx & 7;
    const int l  = (idx >> 3) & 63;
    const int ks = (idx >> 9) & 1;
    const int ct = idx >> 10;
    const int k  = ks * 32 + ((l >> 4) << 3) + j;
    const int c  = ct * 16 + (l & 15);
    sFrag[idx] = f2bf(W2[k * 64 + c]);
  }
  __syncthreads();

  const int w = threadIdx.x >> 6;
  const int l = threadIdx.x & 63;
  const int q = l >> 4;
  const int m = l & 15;
  const int n0 = (blockIdx.x * 4 + w) * 16;
  if (n0 >= N) return;

  short8 bfrag[4][2];
#pragma unroll
  for (int ct = 0; ct < 4; ++ct)
#pragma unroll
    for (int ks = 0; ks < 2; ++ks)
      bfrag[ct][ks] =
          *reinterpret_cast<const short8*>(&sFrag[(ct * 2 + ks) * 512 + l * 8]);

  const int nA = (n0 + m < N) ? (n0 + m) : (N - 1);
  short8 afrag[2];
  afrag[0] = *reinterpret_cast<const short8*>(Hbf + (size_t)nA * 64 + q * 8);
  afrag[1] = *reinterpret_cast<const short8*>(Hbf + (size_t)nA * 64 + 32 + q * 8);

  float dg[4];
#pragma unroll
  for (int r = 0; r < 4; ++r) {
    const int node = n0 + q * 4 + r;
    dg[r] = (node < N) ? (float)cnt[node] : 0.0f;
  }

  f32x4 acc[4];
#pragma unroll
  for (int ct = 0; ct < 4; ++ct) {
    const float bv = b2[ct * 16 + m];
    acc[ct] = (f32x4){dg[0] * bv, dg[1] * bv, dg[2] * bv, dg[3] * bv};
  }

#pragma unroll
  for (int ct = 0; ct < 4; ++ct)
#pragma unroll
    for (int ks = 0; ks < 2; ++ks)
      acc[ct] = __builtin_amdgcn_mfma_f32_16x16x32_bf16(
          afrag[ks], bfrag[ct][ks], acc[ct], 0, 0, 0);

#pragma unroll
  for (int ct = 0; ct < 4; ++ct) {
    const int ch = ct * 16 + m;
#pragma unroll
    for (int r = 0; r < 4; ++r) {
      const int node = n0 + q * 4 + r;
      if (node < N) out[(size_t)node * 64 + ch] = acc[ct][r];
    }
  }
}

// ---------------- fallback (round-1 path, if ws too small) ----------------

__global__ __launch_bounds__(TPB) void edge_mlp_atomic(
    const float* __restrict__ x, const int* __restrict__ ei,
    const float* __restrict__ eattr, const float* __restrict__ W1,
    const float* __restrict__ b1, const float* __restrict__ W2,
    const float* __restrict__ b2, float* __restrict__ out, int E)
{
  __shared__ float sW1[128 * 64];
  __shared__ float sW2[64 * 64];
  __shared__ float sB1[64];
  __shared__ float sB2[64];
  for (int i = threadIdx.x; i < 128 * 64 / 4; i += TPB)
    reinterpret_cast<float4*>(sW1)[i] = reinterpret_cast<const float4*>(W1)[i];
  for (int i = threadIdx.x; i < 64 * 64 / 4; i += TPB)
    reinterpret_cast<float4*>(sW2)[i] = reinterpret_cast<const float4*>(W2)[i];
  if (threadIdx.x < 64) { sB1[threadIdx.x] = b1[threadIdx.x]; sB2[threadIdx.x] = b2[threadIdx.x]; }
  __syncthreads();
  const int e = blockIdx.x * TPB + (int)threadIdx.x;
  if (e >= E) return;
  const int row = ei[e];
  const int col = ei[E + e];
  const float scale = eattr[e];
  float h[64];
#pragma unroll
  for (int o = 0; o < 64; ++o) h[o] = sB1[o];
#pragma unroll
  for (int half = 0; half < 2; ++half) {
    const float4* src = reinterpret_cast<const float4*>(x + (size_t)(half ? col : row) * 64);
    const float sc = half ? 1.0f : scale;
    const float* wb = sW1 + half * 64 * 64;
    for (int kc = 0; kc < 16; ++kc) {
      float4 cv = src[kc];
      cv.x *= sc; cv.y *= sc; cv.z *= sc; cv.w *= sc;
      const float* wr = wb + kc * 4 * 64;
#pragma unroll
      for (int kk = 0; kk < 4; ++kk) {
        const float c = (&cv.x)[kk];
#pragma unroll
        for (int o = 0; o < 64; ++o) h[o] = fmaf(c, wr[kk * 64 + o], h[o]);
      }
    }
  }
#pragma unroll
  for (int o = 0; o < 64; ++o) h[o] = fmaxf(h[o], 0.0f);
  float* outrow = out + (size_t)col * 64;
#pragma unroll
  for (int oc = 0; oc < 4; ++oc) {
    float m[16];
#pragma unroll
    for (int j = 0; j < 16; ++j) m[j] = sB2[oc * 16 + j];
#pragma unroll
    for (int k = 0; k < 64; ++k) {
      const float hk = h[k];
      const float* wr = sW2 + k * 64 + oc * 16;
#pragma unroll
      for (int j = 0; j < 16; ++j) m[j] = fmaf(hk, wr[j], m[j]);
    }
#pragma unroll
    for (int j = 0; j < 16; ++j) atomicAdd(outrow + oc * 16 + j, m[j]);
  }
}

// ---------------- launch ----------------

extern "C" void kernel_launch(void* const* d_in, const int* in_sizes, int n_in,
                              void* d_out, int out_size, void* d_ws, size_t ws_size,
                              hipStream_t stream) {
  const float* x  = (const float*)d_in[0];
  const int*   ei = (const int*)d_in[1];   // [2,E] int32
  const float* ea = (const float*)d_in[2];
  const float* W1 = (const float*)d_in[3];
  const float* b1 = (const float*)d_in[4];
  const float* W2 = (const float*)d_in[5];
  const float* b2 = (const float*)d_in[6];
  float* out = (float*)d_out;
  const int E = in_sizes[2];
  const int N = in_sizes[0] / 64;

  // ws layout: srp[E] u32 | rank[E] | cnt[N] | total(1) | off[N]
  //            | Af8[N*64 u8] | Bpbf[N*64 u16] | Hbf[N*64 u16]
  auto align16 = [](size_t v) { return (v + 15) & ~(size_t)15; };
  size_t o_srp  = 0;
  size_t o_rank = align16(o_srp + (size_t)E * 4);
  size_t o_cnt  = align16(o_rank + (size_t)E * 4);          // cnt + total contiguous
  size_t o_off  = align16(o_cnt + (size_t)(N + 1) * 4);
  size_t o_A    = align16(o_off + (size_t)N * 4);
  size_t o_Bp   = align16(o_A + (size_t)N * 64);
  size_t o_H    = align16(o_Bp + (size_t)N * 128);
  size_t need   = o_H + (size_t)N * 128;

  if (ws_size < need || N > (1 << 17)) {
    hipMemsetAsync(d_out, 0, (size_t)out_size * sizeof(float), stream);
    const int blocks = (E + TPB - 1) / TPB;
    edge_mlp_atomic<<<blocks, TPB, 0, stream>>>(x, ei, ea, W1, b1, W2, b2, out, E);
    return;
  }

  char* ws = (char*)d_ws;
  unsigned int* srp = (unsigned int*)(ws + o_srp);
  int*  rank  = (int*)(ws + o_rank);
  int*  cnt   = (int*)(ws + o_cnt);
  int*  total = cnt + N;
  int*  off   = (int*)(ws + o_off);
  unsigned char*  Af8  = (unsigned char*)(ws + o_A);
  unsigned short* Bpbf = (unsigned short*)(ws + o_Bp);
  unsigned short* Hbf  = (unsigned short*)(ws + o_H);

  hipMemsetAsync(cnt, 0, (size_t)(N + 1) * sizeof(int), stream);

  const int eblocks = (E + TPB - 1) / TPB;
  const int nblocks4 = (4 * N + TPB - 1) / TPB;
  const int bb = (N + TPB - 1) / TPB;             // base-assign blocks
  const int tblocks = ((N + 15) / 16 + 3) / 4;    // precompute tiles

  hist_rank<<<eblocks, TPB, 0, stream>>>(ei, cnt, rank, E);
  base_and_precompute<<<bb + tblocks, TPB, 0, stream>>>(
      x, W1, b1, cnt, off, total, Af8, Bpbf, N, bb);
  scatter_edges<<<eblocks, TPB, 0, stream>>>(ei, ea, off, rank, srp, E);
  node_accum<<<nblocks4, TPB, 0, stream>>>(Af8, (const unsigned int*)Bpbf,
                                           srp, off, cnt, Hbf, N);
  final_mfma<<<tblocks, TPB, 0, stream>>>(Hbf, W2, b2, cnt, out, N);
}